// Round 1
// baseline (486.408 us; speedup 1.0000x reference)
//
#include <hip/hip_runtime.h>

#define AF 128
#define BF 128

// ---------------- GEMM: support[NB,AF] = B[NB,BF] @ W[BF,AF], fp32 ----------------
// 256 threads/block, 64-row x 128-col output tile, K-tile = 32.
// Thread = (trow 0..7 -> 8 rows each, tcol 0..31 -> 4 cols each), acc[8][4].
__global__ __launch_bounds__(256) void gemm_kernel(const float* __restrict__ B,
                                                   const float* __restrict__ W,
                                                   float* __restrict__ C, int NB) {
    __shared__ float Bs[64][33];      // +1 pad: per-k reads across trow hit distinct banks
    __shared__ float Ws[32 * 128];    // stride-16B ds_read_b128 is conflict-free
    const int tid  = threadIdx.x;
    const int tcol = tid & 31;
    const int trow = tid >> 5;
    const int row0 = blockIdx.x * 64;

    float acc[8][4];
    #pragma unroll
    for (int i = 0; i < 8; i++)
        #pragma unroll
        for (int j = 0; j < 4; j++) acc[i][j] = 0.f;

    for (int kk = 0; kk < BF; kk += 32) {
        // stage B tile: 64 rows x 32 k. thread loads 8 consecutive floats of one row.
        {
            int lr = tid >> 2;
            int ks = (tid & 3) * 8;
            int gr = row0 + lr;
            const float* src = B + (size_t)gr * BF + kk + ks;
            #pragma unroll
            for (int i = 0; i < 8; i++) Bs[lr][ks + i] = (gr < NB) ? src[i] : 0.f;
        }
        // stage W tile: 32 k x 128 c. thread loads 16 consecutive floats (4x float4).
        {
            int lk = tid >> 3;
            int cs = (tid & 7) * 16;
            const float4* src = (const float4*)(W + (size_t)(kk + lk) * AF + cs);
            float4* dst = (float4*)(Ws + lk * 128 + cs);
            #pragma unroll
            for (int i = 0; i < 4; i++) dst[i] = src[i];
        }
        __syncthreads();
        #pragma unroll
        for (int k = 0; k < 32; k++) {
            float4 w4 = *(const float4*)(Ws + k * 128 + tcol * 4);
            #pragma unroll
            for (int i = 0; i < 8; i++) {
                float b = Bs[trow * 8 + i][k];
                acc[i][0] += b * w4.x;
                acc[i][1] += b * w4.y;
                acc[i][2] += b * w4.z;
                acc[i][3] += b * w4.w;
            }
        }
        __syncthreads();
    }
    #pragma unroll
    for (int i = 0; i < 8; i++) {
        int r = row0 + trow * 8 + i;
        if (r < NB) {
            float4 v = {acc[i][0], acc[i][1], acc[i][2], acc[i][3]};
            *(float4*)(C + (size_t)r * AF + tcol * 4) = v;
        }
    }
}

// ---------------- CSR construction ----------------
__global__ void hist_kernel(const int* __restrict__ rows, int* __restrict__ cnt, int NE) {
    int i = blockIdx.x * blockDim.x + threadIdx.x;
    if (i < NE) atomicAdd(&cnt[rows[i]], 1);
}

// per-256-block inclusive scan of counts -> exclusive partials + block totals
__global__ __launch_bounds__(256) void scanA_kernel(const int* __restrict__ cnt,
                                                    int* __restrict__ partial,
                                                    int* __restrict__ bsum, int NA) {
    __shared__ int s[256];
    int tid = threadIdx.x;
    int i = blockIdx.x * 256 + tid;
    int v = (i < NA) ? cnt[i] : 0;
    int x = v;
    s[tid] = x;
    __syncthreads();
    #pragma unroll
    for (int off = 1; off < 256; off <<= 1) {
        int t = (tid >= off) ? s[tid - off] : 0;
        __syncthreads();
        x += t;
        s[tid] = x;
        __syncthreads();
    }
    if (i < NA) partial[i] = x - v;         // exclusive within block
    if (tid == 255) bsum[blockIdx.x] = x;   // block total
}

// single-block scan of block totals (n <= 512; NA=100000 -> n=391)
__global__ __launch_bounds__(512) void scanB_kernel(int* __restrict__ bsum, int n) {
    __shared__ int s[512];
    int tid = threadIdx.x;
    int v = (tid < n) ? bsum[tid] : 0;
    int x = v;
    s[tid] = x;
    __syncthreads();
    #pragma unroll
    for (int off = 1; off < 512; off <<= 1) {
        int t = (tid >= off) ? s[tid - off] : 0;
        __syncthreads();
        x += t;
        s[tid] = x;
        __syncthreads();
    }
    if (tid < n) bsum[tid] = x - v;         // exclusive
}

// finalize row_start (in place) and reset cursor = row_start
__global__ void scanC_kernel(int* __restrict__ row_start, int* __restrict__ cursor,
                             const int* __restrict__ bsum, int NA, int NE) {
    int i = blockIdx.x * blockDim.x + threadIdx.x;
    if (i < NA) {
        int v = row_start[i] + bsum[i >> 8];
        row_start[i] = v;
        cursor[i] = v;
    }
    if (i == 0) row_start[NA] = NE;
}

__global__ void scatter_kernel(const int* __restrict__ rows, const int* __restrict__ cols,
                               const float* __restrict__ vals, int* __restrict__ cursor,
                               int* __restrict__ csr_col, float* __restrict__ csr_val, int NE) {
    int i = blockIdx.x * blockDim.x + threadIdx.x;
    if (i < NE) {
        int r = rows[i];
        int pos = atomicAdd(&cursor[r], 1);
        csr_col[pos] = cols[i];
        csr_val[pos] = vals[i];
    }
}

// ---------------- atomic-free gather-reduce: one wave per output row ----------------
__global__ __launch_bounds__(256) void gather_kernel(const float* __restrict__ support,
                                                     const int* __restrict__ row_start,
                                                     const int* __restrict__ csr_col,
                                                     const float* __restrict__ csr_val,
                                                     const float* __restrict__ bias,
                                                     float* __restrict__ out, int NA) {
    int wave = threadIdx.x >> 6;
    int lane = threadIdx.x & 63;
    int r = blockIdx.x * 4 + wave;
    if (r >= NA) return;
    int e0 = row_start[r];
    int e1 = row_start[r + 1];
    int c2 = lane * 2;
    float2 acc = {0.f, 0.f};
    for (int e = e0; e < e1; e++) {
        int col = csr_col[e];             // wave-uniform load (coalesces to 1 request)
        float v = csr_val[e];
        const float2 sv = *(const float2*)(support + (size_t)col * AF + c2);
        acc.x += v * sv.x;
        acc.y += v * sv.y;
    }
    const float2 b = *(const float2*)(bias + c2);
    float2 o = {acc.x + b.x, acc.y + b.y};
    *(float2*)(out + (size_t)r * AF + c2) = o;
}

extern "C" void kernel_launch(void* const* d_in, const int* in_sizes, int n_in,
                              void* d_out, int out_size, void* d_ws, size_t ws_size,
                              hipStream_t stream) {
    const float* b_input  = (const float*)d_in[0];
    const int*   edge_rows = (const int*)d_in[1];
    const int*   edge_cols = (const int*)d_in[2];
    const float* edge_vals = (const float*)d_in[3];
    const float* a_weight  = (const float*)d_in[4];
    const float* a_bias    = (const float*)d_in[5];
    const int NB = in_sizes[0] / BF;
    const int NE = in_sizes[1];
    const int NA = out_size / AF;
    float* out = (float*)d_out;

    // workspace layout (~64.8 MB total)
    char* ws = (char*)d_ws;
    size_t off = 0;
    float* support  = (float*)(ws + off); off += (size_t)NB * AF * sizeof(float);
    int* row_start  = (int*)(ws + off);   off += ((size_t)NA + 16) * sizeof(int);
    int* cursor     = (int*)(ws + off);   off += ((size_t)NA + 16) * sizeof(int);
    int* bsum       = (int*)(ws + off);   off += 512 * sizeof(int);
    int* csr_col    = (int*)(ws + off);   off += (size_t)NE * sizeof(int);
    float* csr_val  = (float*)(ws + off); off += (size_t)NE * sizeof(float);
    (void)ws_size; (void)n_in;

    hipMemsetAsync(cursor, 0, (size_t)NA * sizeof(int), stream);

    gemm_kernel<<<(NB + 63) / 64, 256, 0, stream>>>(b_input, a_weight, support, NB);
    hist_kernel<<<(NE + 255) / 256, 256, 0, stream>>>(edge_rows, cursor, NE);
    int nsA = (NA + 255) / 256;
    scanA_kernel<<<nsA, 256, 0, stream>>>(cursor, row_start, bsum, NA);
    scanB_kernel<<<1, 512, 0, stream>>>(bsum, nsA);
    scanC_kernel<<<nsA, 256, 0, stream>>>(row_start, cursor, bsum, NA, NE);
    scatter_kernel<<<(NE + 255) / 256, 256, 0, stream>>>(edge_rows, edge_cols, edge_vals,
                                                         cursor, csr_col, csr_val, NE);
    gather_kernel<<<(NA + 3) / 4, 256, 0, stream>>>(support, row_start, csr_col, csr_val,
                                                    a_bias, out, NA);
}

// Round 2
// 377.830 us; speedup vs baseline: 1.2874x; 1.2874x over previous
//
#include <hip/hip_runtime.h>

#define AF 128
#define BF 128

typedef __attribute__((ext_vector_type(8))) short bf16x8;
typedef __attribute__((ext_vector_type(4))) float f32x4;

__device__ inline unsigned short f2bf(float f) {
    unsigned int u = __float_as_uint(f);
    u += 0x7FFF + ((u >> 16) & 1);          // round-to-nearest-even
    return (unsigned short)(u >> 16);
}
__device__ inline float bflo(unsigned int u) { return __uint_as_float(u << 16); }
__device__ inline float bfhi(unsigned int u) { return __uint_as_float(u & 0xFFFF0000u); }

// ---- one-time: Wt[n][k] = bf16(W[k][n]), 128x128 ----
__global__ void wtrans_kernel(const float* __restrict__ W, unsigned short* __restrict__ Wt) {
    int idx = blockIdx.x * 256 + threadIdx.x;   // grid 64 x 256 = 16384
    int n = idx & 127, k = idx >> 7;
    Wt[n * 128 + k] = f2bf(W[(size_t)k * 128 + n]);
}

// ---- MFMA GEMM: Sup[NB][128] (bf16) = Bin[NB][128] @ W ----
// block = 256 (4 waves), 64 rows/block, whole K=128 in LDS, no K-loop.
__global__ __launch_bounds__(256) void gemm_mfma_kernel(const float* __restrict__ Bin,
                                                        const unsigned short* __restrict__ Wt,
                                                        unsigned short* __restrict__ Sup, int NB) {
    __shared__ unsigned short As[64][136];    // pad 136: b128 reads -> 2-way (free)
    __shared__ unsigned short Ws[128][136];
    const int tid = threadIdx.x;
    const int lane = tid & 63;
    const int wave = tid >> 6;
    const int row0 = blockIdx.x * 64;

    // stage A tile (fp32 -> bf16): 4 threads per row, 32 floats each
    {
        int lr = tid >> 2;
        int ks = (tid & 3) * 32;
        int gr = row0 + lr;
        if (gr < NB) {
            const float4* src = (const float4*)(Bin + (size_t)gr * BF + ks);
            #pragma unroll
            for (int i = 0; i < 8; i++) {
                float4 v = src[i];
                int kk = ks + i * 4;
                As[lr][kk + 0] = f2bf(v.x); As[lr][kk + 1] = f2bf(v.y);
                As[lr][kk + 2] = f2bf(v.z); As[lr][kk + 3] = f2bf(v.w);
            }
        } else {
            #pragma unroll
            for (int i = 0; i < 32; i++) As[lr][ks + i] = 0;
        }
    }
    // stage Wt (already bf16): thread copies 128 B
    {
        int r = tid >> 1;
        int c = (tid & 1) * 64;
        const uint4* src = (const uint4*)(Wt + r * 128 + c);
        uint4* dst = (uint4*)(&Ws[r][c]);
        #pragma unroll
        for (int i = 0; i < 8; i++) dst[i] = src[i];
    }
    __syncthreads();

    const int m = lane & 15;
    const int quad = lane >> 4;

    bf16x8 af[4];
    #pragma unroll
    for (int ks = 0; ks < 4; ks++)
        af[ks] = *(const bf16x8*)(&As[wave * 16 + m][ks * 32 + quad * 8]);

    #pragma unroll
    for (int nt = 0; nt < 8; nt++) {
        f32x4 acc = {0.f, 0.f, 0.f, 0.f};
        #pragma unroll
        for (int ks = 0; ks < 4; ks++) {
            bf16x8 bf = *(const bf16x8*)(&Ws[nt * 16 + m][ks * 32 + quad * 8]);
            acc = __builtin_amdgcn_mfma_f32_16x16x32_bf16(af[ks], bf, acc, 0, 0, 0);
        }
        #pragma unroll
        for (int r = 0; r < 4; r++) {
            int row = row0 + wave * 16 + quad * 4 + r;
            if (row < NB) Sup[(size_t)row * AF + nt * 16 + m] = f2bf(acc[r]);
        }
    }
}

// ---------------- CSR construction ----------------
__global__ void hist_kernel(const int* __restrict__ rows, int* __restrict__ cnt, int NE) {
    int i = blockIdx.x * blockDim.x + threadIdx.x;
    if (i < NE) atomicAdd(&cnt[rows[i]], 1);
}

__global__ __launch_bounds__(256) void scanA_kernel(const int* __restrict__ cnt,
                                                    int* __restrict__ partial,
                                                    int* __restrict__ bsum, int NA) {
    __shared__ int s[256];
    int tid = threadIdx.x;
    int i = blockIdx.x * 256 + tid;
    int v = (i < NA) ? cnt[i] : 0;
    int x = v;
    s[tid] = x;
    __syncthreads();
    #pragma unroll
    for (int off = 1; off < 256; off <<= 1) {
        int t = (tid >= off) ? s[tid - off] : 0;
        __syncthreads();
        x += t;
        s[tid] = x;
        __syncthreads();
    }
    if (i < NA) partial[i] = x - v;
    if (tid == 255) bsum[blockIdx.x] = x;
}

__global__ __launch_bounds__(512) void scanB_kernel(int* __restrict__ bsum, int n) {
    __shared__ int s[512];
    int tid = threadIdx.x;
    int v = (tid < n) ? bsum[tid] : 0;
    int x = v;
    s[tid] = x;
    __syncthreads();
    #pragma unroll
    for (int off = 1; off < 512; off <<= 1) {
        int t = (tid >= off) ? s[tid - off] : 0;
        __syncthreads();
        x += t;
        s[tid] = x;
        __syncthreads();
    }
    if (tid < n) bsum[tid] = x - v;
}

__global__ void scanC_kernel(int* __restrict__ row_start, int* __restrict__ cursor,
                             const int* __restrict__ bsum, int NA, int NE) {
    int i = blockIdx.x * blockDim.x + threadIdx.x;
    if (i < NA) {
        int v = row_start[i] + bsum[i >> 8];
        row_start[i] = v;
        cursor[i] = v;
    }
    if (i == 0) row_start[NA] = NE;
}

__global__ void scatter_kernel(const int* __restrict__ rows, const int* __restrict__ cols,
                               const float* __restrict__ vals, int* __restrict__ cursor,
                               int2* __restrict__ csr, int NE) {
    int i = blockIdx.x * blockDim.x + threadIdx.x;
    if (i < NE) {
        int r = rows[i];
        int pos = atomicAdd(&cursor[r], 1);
        csr[pos] = make_int2(cols[i], __float_as_int(vals[i]));
    }
}

// ---- gather-reduce: one wave per row, bf16 support, unroll-4 for MLP ----
__global__ __launch_bounds__(256) void gather_kernel(const unsigned short* __restrict__ Sup,
                                                     const int* __restrict__ row_start,
                                                     const int2* __restrict__ csr,
                                                     const float* __restrict__ bias,
                                                     float* __restrict__ out, int NA) {
    int wave = threadIdx.x >> 6;
    int lane = threadIdx.x & 63;
    int r = blockIdx.x * 4 + wave;
    if (r >= NA) return;
    int e0 = row_start[r];
    int e1 = row_start[r + 1];
    int foff = lane * 2;
    float accx = 0.f, accy = 0.f;
    int e = e0;
    for (; e + 4 <= e1; e += 4) {
        int2 p0 = csr[e], p1 = csr[e + 1], p2 = csr[e + 2], p3 = csr[e + 3];
        unsigned int s0 = *(const unsigned int*)(Sup + (size_t)p0.x * AF + foff);
        unsigned int s1 = *(const unsigned int*)(Sup + (size_t)p1.x * AF + foff);
        unsigned int s2 = *(const unsigned int*)(Sup + (size_t)p2.x * AF + foff);
        unsigned int s3 = *(const unsigned int*)(Sup + (size_t)p3.x * AF + foff);
        float v0 = __int_as_float(p0.y), v1 = __int_as_float(p1.y);
        float v2 = __int_as_float(p2.y), v3 = __int_as_float(p3.y);
        accx += v0 * bflo(s0) + v1 * bflo(s1) + v2 * bflo(s2) + v3 * bflo(s3);
        accy += v0 * bfhi(s0) + v1 * bfhi(s1) + v2 * bfhi(s2) + v3 * bfhi(s3);
    }
    for (; e < e1; e++) {
        int2 p = csr[e];
        unsigned int s = *(const unsigned int*)(Sup + (size_t)p.x * AF + foff);
        float v = __int_as_float(p.y);
        accx += v * bflo(s);
        accy += v * bfhi(s);
    }
    const float2 b = *(const float2*)(bias + foff);
    float2 o = {accx + b.x, accy + b.y};
    *(float2*)(out + (size_t)r * AF + foff) = o;
}

extern "C" void kernel_launch(void* const* d_in, const int* in_sizes, int n_in,
                              void* d_out, int out_size, void* d_ws, size_t ws_size,
                              hipStream_t stream) {
    const float* b_input   = (const float*)d_in[0];
    const int*   edge_rows = (const int*)d_in[1];
    const int*   edge_cols = (const int*)d_in[2];
    const float* edge_vals = (const float*)d_in[3];
    const float* a_weight  = (const float*)d_in[4];
    const float* a_bias    = (const float*)d_in[5];
    const int NB = in_sizes[0] / BF;
    const int NE = in_sizes[1];
    const int NA = out_size / AF;
    float* out = (float*)d_out;

    // workspace layout (~38.5 MB)
    char* ws = (char*)d_ws;
    size_t off = 0;
    unsigned short* support = (unsigned short*)(ws + off); off += (size_t)NB * AF * sizeof(unsigned short);
    unsigned short* Wt      = (unsigned short*)(ws + off); off += (size_t)BF * AF * sizeof(unsigned short);
    int* row_start = (int*)(ws + off); off += ((size_t)NA + 16) * sizeof(int);
    int* cursor    = (int*)(ws + off); off += ((size_t)NA + 16) * sizeof(int);
    int* bsum      = (int*)(ws + off); off += 512 * sizeof(int);
    int2* csr      = (int2*)(ws + off); off += (size_t)NE * sizeof(int2);
    (void)ws_size; (void)n_in;

    hipMemsetAsync(cursor, 0, (size_t)NA * sizeof(int), stream);

    wtrans_kernel<<<64, 256, 0, stream>>>(a_weight, Wt);
    gemm_mfma_kernel<<<(NB + 63) / 64, 256, 0, stream>>>(b_input, Wt, support, NB);
    hist_kernel<<<(NE + 255) / 256, 256, 0, stream>>>(edge_rows, cursor, NE);
    int nsA = (NA + 255) / 256;
    scanA_kernel<<<nsA, 256, 0, stream>>>(cursor, row_start, bsum, NA);
    scanB_kernel<<<1, 512, 0, stream>>>(bsum, nsA);
    scanC_kernel<<<nsA, 256, 0, stream>>>(row_start, cursor, bsum, NA, NE);
    scatter_kernel<<<(NE + 255) / 256, 256, 0, stream>>>(edge_rows, edge_cols, edge_vals,
                                                         cursor, csr, NE);
    gather_kernel<<<(NA + 3) / 4, 256, 0, stream>>>(support, row_start, csr,
                                                    a_bias, out, NA);
}